// Round 1
// baseline (130.523 us; speedup 1.0000x reference)
//
#include <hip/hip_runtime.h>

// InversePreEmphasis: h_t = tanh(x_t + 0.97*h_{t-1}) along T, per row.
// B=256 rows, T=131072. Chunked-parallel with warm-up (Jacobian <= 0.97/step).

constexpr int B = 256;
constexpr int T = 131072;
constexpr int S = 1024;        // chunk length (output steps per thread)
constexpr int C = T / S;       // 128 chunks per row
constexpr int W = 512;         // warm-up steps; 0.97^512 ~ 2e-7 residual

// tanh(x + 0.97h) = 1 - 2/(exp2(g*x + 0.97*g*h) + 1),  g = 2*log2(e)
constexpr float GLN  = 2.885390081777927f;          // 2*log2(e)
constexpr float CGLN = 0.97f * 2.885390081777927f;  // 0.97 * g

__device__ __forceinline__ float tanh_step(float gx, float h) {
    float e = __builtin_amdgcn_exp2f(fmaf(CGLN, h, gx));
    float r = __builtin_amdgcn_rcpf(e + 1.0f);
    return fmaf(-2.0f, r, 1.0f);
}

__global__ __launch_bounds__(256) void ipe_scan_kernel(const float* __restrict__ x,
                                                       float* __restrict__ y) {
    const int tid = blockIdx.x * blockDim.x + threadIdx.x;
    const int b = tid / C;
    const int c = tid % C;
    const float* xr = x + (size_t)b * T;
    float*       yr = y + (size_t)b * T;

    const int start = c * S;
    float h = 0.0f;

    // ---- warm-up (discarded); c==0 starts exactly from h0=0 ----
    int w0 = start - W;
    if (w0 < 0) w0 = 0;
    for (int j = w0; j < start; j += 4) {
        float4 v = *reinterpret_cast<const float4*>(xr + j);
        h = tanh_step(v.x * GLN, h);
        h = tanh_step(v.y * GLN, h);
        h = tanh_step(v.z * GLN, h);
        h = tanh_step(v.w * GLN, h);
    }

    // ---- body: compute and store ----
    for (int j = start; j < start + S; j += 4) {
        float4 v = *reinterpret_cast<const float4*>(xr + j);
        float4 o;
        o.x = h = tanh_step(v.x * GLN, h);
        o.y = h = tanh_step(v.y * GLN, h);
        o.z = h = tanh_step(v.z * GLN, h);
        o.w = h = tanh_step(v.w * GLN, h);
        *reinterpret_cast<float4*>(yr + j) = o;
    }
}

extern "C" void kernel_launch(void* const* d_in, const int* in_sizes, int n_in,
                              void* d_out, int out_size, void* d_ws, size_t ws_size,
                              hipStream_t stream) {
    const float* x = (const float*)d_in[0];
    float*       y = (float*)d_out;
    const int total_threads = B * C;          // 32768
    const int block = 256;
    const int grid = total_threads / block;   // 128
    ipe_scan_kernel<<<grid, block, 0, stream>>>(x, y);
}

// Round 3
// 117.475 us; speedup vs baseline: 1.1111x; 1.1111x over previous
//
#include <hip/hip_runtime.h>

// InversePreEmphasis: h_t = tanh(x_t + 0.97*h_{t-1}) along T, per row.
// Chunked-parallel with warm-up (per-step Jacobian <= 0.97).
// R2 fix: warm-up length = min(W, start) so early chunks use the exact
// prefix from x[0] instead of overrunning into their own body.

constexpr int Bn = 256;
constexpr int T  = 131072;
constexpr int S  = 128;         // output elems per thread
constexpr int C  = T / S;       // 1024 chunks per row
constexpr int W  = 256;         // warm-up steps: 2*0.97^256 ~ 8e-4
constexpr int G  = 16;          // group size (4x float4)

// tanh(x + 0.97h) = 1 - 2*rcp(exp2(g*x + 0.97*g*h) + 1),  g = 2*log2(e)
// state r:  h = 1 - 2r;  t_k = fma(N2CG, r_{k-1}, gx_k);  gx_k = fma(GLN, x_k, CGLN)
constexpr float GLN  = 2.885390081777927f;          // 2*log2(e)
constexpr float CGLN = 0.97f * 2.885390081777927f;
constexpr float N2CG = -2.0f * 0.97f * 2.885390081777927f;

struct Grp { float4 a, b, c, d; };

__device__ __forceinline__ Grp ldg16(const float* p) {
    Grp g;
    g.a = *reinterpret_cast<const float4*>(p);
    g.b = *reinterpret_cast<const float4*>(p + 4);
    g.c = *reinterpret_cast<const float4*>(p + 8);
    g.d = *reinterpret_cast<const float4*>(p + 12);
    return g;
}

__device__ __forceinline__ void unpack(const Grp& v, float* f) {
    f[0]=v.a.x;  f[1]=v.a.y;  f[2]=v.a.z;  f[3]=v.a.w;
    f[4]=v.b.x;  f[5]=v.b.y;  f[6]=v.b.z;  f[7]=v.b.w;
    f[8]=v.c.x;  f[9]=v.c.y;  f[10]=v.c.z; f[11]=v.c.w;
    f[12]=v.d.x; f[13]=v.d.y; f[14]=v.d.z; f[15]=v.d.w;
}

template <bool OUT>
__device__ __forceinline__ void chain16(float& r, const Grp& v, float* h) {
    float f[G], gx[G];
    unpack(v, f);
#pragma unroll
    for (int i = 0; i < G; ++i) gx[i] = fmaf(GLN, f[i], CGLN);  // off-chain
#pragma unroll
    for (int i = 0; i < G; ++i) {
        float t = fmaf(N2CG, r, gx[i]);          // chain op 1
        float e = __builtin_amdgcn_exp2f(t);     // chain op 2
        r = __builtin_amdgcn_rcpf(e + 1.0f);     // chain ops 3,4
        if (OUT) h[i] = fmaf(-2.0f, r, 1.0f);    // off-chain
    }
}

__device__ __forceinline__ void st16(float* p, const float* h) {
    *reinterpret_cast<float4*>(p)      = make_float4(h[0],  h[1],  h[2],  h[3]);
    *reinterpret_cast<float4*>(p + 4)  = make_float4(h[4],  h[5],  h[6],  h[7]);
    *reinterpret_cast<float4*>(p + 8)  = make_float4(h[8],  h[9],  h[10], h[11]);
    *reinterpret_cast<float4*>(p + 12) = make_float4(h[12], h[13], h[14], h[15]);
}

__global__ __launch_bounds__(256, 4) void ipe_scan_kernel(const float* __restrict__ x,
                                                          float* __restrict__ y) {
    const int tid = blockIdx.x * blockDim.x + threadIdx.x;
    const int b = tid / C;
    const int c = tid % C;
    const float* xr = x + (size_t)b * T;
    const int start = c * S;

    // Warm-up covers [start-Wc, start); exact prefix when start < W.
    const int Wc = start < W ? start : W;
    const float* pw = xr + (start - Wc);
    const float* pb = xr + start;
    float*       po = y + (size_t)b * T + start;

    float r = 0.5f;           // h = 1 - 2r = 0

    Grp A = ldg16(pb);        // body group 0 preloaded to bridge the boundary

    // ---- warm-up (discarded), with 1-group prefetch ----
    const int nw = Wc / G;
    if (nw > 0) {
        Grp w = ldg16(pw);
#pragma unroll 1
        for (int g = 0; g < nw - 1; ++g) {
            Grp n = ldg16(pw + (g + 1) * G);
            chain16<false>(r, w, nullptr);
            w = n;
        }
        chain16<false>(r, w, nullptr);
    }

    // ---- body: compute + store, with 1-group prefetch ----
#pragma unroll 1
    for (int g = 0; g < S / G - 1; ++g) {
        Grp n = ldg16(pb + (g + 1) * G);
        float h[G];
        chain16<true>(r, A, h);
        st16(po + g * G, h);
        A = n;
    }
    {
        float h[G];
        chain16<true>(r, A, h);
        st16(po + (S / G - 1) * G, h);
    }
}

extern "C" void kernel_launch(void* const* d_in, const int* in_sizes, int n_in,
                              void* d_out, int out_size, void* d_ws, size_t ws_size,
                              hipStream_t stream) {
    const float* x = (const float*)d_in[0];
    float*       y = (float*)d_out;
    const int total_threads = Bn * C;          // 262144
    const int block = 256;
    const int grid = total_threads / block;    // 1024
    ipe_scan_kernel<<<grid, block, 0, stream>>>(x, y);
}

// Round 4
// 75.724 us; speedup vs baseline: 1.7237x; 1.5514x over previous
//
#include <hip/hip_runtime.h>

// InversePreEmphasis: h_t = tanh(x_t + 0.97*h_{t-1}) along T, per row.
// Chunked-parallel with warm-up (per-step contraction <= 0.97, typ ~0.5).
// R4: W=64, G=32 (128B groups), forced prefetch via volatile asm
// global_load_dwordx4 + counted s_waitcnt vmcnt(N) + sched_barrier(0).

constexpr int Bn = 256;
constexpr int T  = 131072;
constexpr int S  = 128;        // outputs per thread
constexpr int C  = T / S;      // 1024 chunks per row
constexpr int W  = 64;         // warm-up steps (2 groups)
constexpr int G  = 32;         // group = 128 bytes per thread

// tanh(x + 0.97h) = 1 - 2*rcp(exp2(g*x + 0.97*g*h) + 1),  g = 2*log2(e)
// state r: h = 1-2r;  t_k = fma(N2CG, r_{k-1}, gx_k);  gx_k = fma(GLN, x_k, CGLN)
constexpr float GLN  = 2.885390081777927f;          // 2*log2(e)
constexpr float CGLN = 0.97f * 2.885390081777927f;
constexpr float N2CG = -2.0f * 0.97f * 2.885390081777927f;

struct G8 { float4 v[8]; };

// Volatile asm load: compiler cannot sink it; stays where issued.
#define LD4(dst, ptr, off) \
    asm volatile("global_load_dwordx4 %0, %1, off offset:" #off \
                 : "=&v"(dst) : "v"(ptr) : "memory")

// Counted wait + scheduling fence (rule #18: consumers must not hoist past).
#define WAITV(n) do { \
    asm volatile("s_waitcnt vmcnt(" #n ")" ::: "memory"); \
    __builtin_amdgcn_sched_barrier(0); \
} while (0)

__device__ __forceinline__ void ldgrp(G8& g, const float* p) {
    LD4(g.v[0], p, 0);   LD4(g.v[1], p, 16);  LD4(g.v[2], p, 32);
    LD4(g.v[3], p, 48);  LD4(g.v[4], p, 64);  LD4(g.v[5], p, 80);
    LD4(g.v[6], p, 96);  LD4(g.v[7], p, 112);
}

template <bool OUT>
__device__ __forceinline__ void chainG(float& r, const G8& g, float* po) {
    float gx[G];
#pragma unroll
    for (int k = 0; k < 8; ++k) {             // off-chain pre-activations
        gx[4*k+0] = fmaf(GLN, g.v[k].x, CGLN);
        gx[4*k+1] = fmaf(GLN, g.v[k].y, CGLN);
        gx[4*k+2] = fmaf(GLN, g.v[k].z, CGLN);
        gx[4*k+3] = fmaf(GLN, g.v[k].w, CGLN);
    }
#pragma unroll
    for (int k = 0; k < 8; ++k) {
        float4 o; float t, e;
        t = fmaf(N2CG, r, gx[4*k+0]); e = __builtin_amdgcn_exp2f(t);
        r = __builtin_amdgcn_rcpf(e + 1.0f); o.x = fmaf(-2.0f, r, 1.0f);
        t = fmaf(N2CG, r, gx[4*k+1]); e = __builtin_amdgcn_exp2f(t);
        r = __builtin_amdgcn_rcpf(e + 1.0f); o.y = fmaf(-2.0f, r, 1.0f);
        t = fmaf(N2CG, r, gx[4*k+2]); e = __builtin_amdgcn_exp2f(t);
        r = __builtin_amdgcn_rcpf(e + 1.0f); o.z = fmaf(-2.0f, r, 1.0f);
        t = fmaf(N2CG, r, gx[4*k+3]); e = __builtin_amdgcn_exp2f(t);
        r = __builtin_amdgcn_rcpf(e + 1.0f); o.w = fmaf(-2.0f, r, 1.0f);
        if constexpr (OUT) *reinterpret_cast<float4*>(po + 4*k) = o;
    }
}

__global__ __launch_bounds__(256, 4) void ipe_scan_kernel(const float* __restrict__ x,
                                                          float* __restrict__ y) {
    const int tid = blockIdx.x * blockDim.x + threadIdx.x;
    const int b = tid / C;
    const int c = tid % C;
    const float* xr = x + (size_t)b * T;
    const int start = c * S;

    // c==0: dummy warm-up over x[0..W) (valid memory), state reset below.
    const float* pw = xr + (start >= W ? start - W : 0);
    const float* pb = xr + start;
    float*       po = y + (size_t)b * T + start;

    G8 w0, w1, A, Bb;
    ldgrp(w0, pw);          //  8 outstanding
    ldgrp(w1, pw + G);      // 16
    ldgrp(A,  pb);          // 24

    float r = 0.5f;         // h = 1 - 2r = 0

    WAITV(16);              // w0 ready (any older pending load forces >16)
    chainG<false>(r, w0, nullptr);
    WAITV(8);               // w1 ready
    chainG<false>(r, w1, nullptr);

    if (c == 0) r = 0.5f;   // exact h0 = 0 for the first chunk

    // ---- body: 4 groups of 32, ping-pong A/Bb, prefetch depth 1 ----
    ldgrp(Bb, pb + G);
    WAITV(8);               // A ready
    chainG<true>(r, A, po);

    ldgrp(A, pb + 2 * G);
    WAITV(8);               // Bb ready (stores only inflate the count)
    chainG<true>(r, Bb, po + G);

    ldgrp(Bb, pb + 3 * G);
    WAITV(8);               // A ready
    chainG<true>(r, A, po + 2 * G);

    WAITV(0);               // Bb ready
    chainG<true>(r, Bb, po + 3 * G);
}

extern "C" void kernel_launch(void* const* d_in, const int* in_sizes, int n_in,
                              void* d_out, int out_size, void* d_ws, size_t ws_size,
                              hipStream_t stream) {
    const float* x = (const float*)d_in[0];
    float*       y = (float*)d_out;
    const int total_threads = Bn * C;          // 262144
    const int block = 256;
    const int grid = total_threads / block;    // 1024
    ipe_scan_kernel<<<grid, block, 0, stream>>>(x, y);
}